// Round 1
// baseline (318.838 us; speedup 1.0000x reference)
//
#include <hip/hip_runtime.h>
#include <hip/hip_bf16.h>

#define EMBED_DIM 4096
#define PROJ_DIM  1024
#define NROWS     8192

typedef __bf16 bf16x8_t __attribute__((ext_vector_type(8)));
typedef float  f32x4_t  __attribute__((ext_vector_type(4)));
typedef unsigned short ushort8_t __attribute__((ext_vector_type(8)));

__device__ __forceinline__ unsigned short f2bf(float f) {
  unsigned u = __builtin_bit_cast(unsigned, f);
  u += 0x7fffu + ((u >> 16) & 1u);   // round-to-nearest-even
  return (unsigned short)(u >> 16);
}

__device__ __forceinline__ void stage16(const void* g, void* l) {
  __builtin_amdgcn_global_load_lds(
      (const __attribute__((address_space(1))) unsigned int*)g,
      (__attribute__((address_space(3))) unsigned int*)l, 16, 0, 0);
}

// ---- Wb = bf16(W) [4096,1024]; WTb = bf16(W^T) [1024,4096] ----
__global__ __launch_bounds__(256) void prep_w(const float* __restrict__ W,
                                              unsigned short* __restrict__ Wb,
                                              unsigned short* __restrict__ WTb) {
  __shared__ float t[32][33];
  const int px = threadIdx.x & 31;
  const int ty = threadIdx.x >> 5;   // 0..7
  const int p0 = blockIdx.x * 32;
  const int d0 = blockIdx.y * 32;
#pragma unroll
  for (int i = 0; i < 32; i += 8) {
    float v = W[(size_t)(d0 + ty + i) * PROJ_DIM + p0 + px];
    t[ty + i][px] = v;
    Wb[(size_t)(d0 + ty + i) * PROJ_DIM + p0 + px] = f2bf(v);
  }
  __syncthreads();
#pragma unroll
  for (int i = 0; i < 32; i += 8) {
    WTb[(size_t)(p0 + ty + i) * EMBED_DIM + d0 + px] = f2bf(t[px][ty + i]);
  }
}

// ---- delta_bf16 = bf16(source - base), vectorized 8 elems/thread ----
__global__ __launch_bounds__(256) void make_delta(const float4* __restrict__ b,
                                                  const float4* __restrict__ s,
                                                  ushort8_t* __restrict__ d, int n8) {
  for (int i = blockIdx.x * blockDim.x + threadIdx.x; i < n8;
       i += gridDim.x * blockDim.x) {
    float4 b0 = b[2 * i], b1 = b[2 * i + 1];
    float4 s0 = s[2 * i], s1 = s[2 * i + 1];
    ushort8_t o;
    o[0] = f2bf(s0.x - b0.x); o[1] = f2bf(s0.y - b0.y);
    o[2] = f2bf(s0.z - b0.z); o[3] = f2bf(s0.w - b0.w);
    o[4] = f2bf(s1.x - b1.x); o[5] = f2bf(s1.y - b1.y);
    o[6] = f2bf(s1.z - b1.z); o[7] = f2bf(s1.w - b1.w);
    d[i] = o;
  }
}

// ---- C[M,NC] = A[M,K] * Bt[NC,K]^T  (both bf16, f32 accumulate) ----
// EPI==1: write Yb bf16 with per-row partition mask (GEMM1)
// EPI==2: write out = base + C (GEMM2)
#define BM 128
#define BN 128
#define BK 64

template <int EPI, int KDIM>
__global__ __launch_bounds__(256) void gemm_bt(
    const unsigned short* __restrict__ A,   // [M, KDIM] bf16 bits
    const unsigned short* __restrict__ Bt,  // [NC, KDIM] bf16 bits
    const int* __restrict__ subs,           // EPI==1: [M,2]
    unsigned short* __restrict__ Yb,        // EPI==1: [M, 1024] bf16
    const float* __restrict__ base,         // EPI==2
    float* __restrict__ out) {              // EPI==2: [M, 4096]
  __shared__ __attribute__((aligned(16))) __bf16 As[BM * BK];
  __shared__ __attribute__((aligned(16))) __bf16 Bs[BN * BK];

  const int tid  = threadIdx.x;
  const int lane = tid & 63;
  const int wave = tid >> 6;
  const int wm   = wave >> 1;   // 2x2 wave grid, 64x64 per wave
  const int wn   = wave & 1;
  const int m0   = blockIdx.x * BM;
  const int n0   = blockIdx.y * BN;

  const unsigned short* gA = A  + (size_t)m0 * KDIM;
  const unsigned short* gB = Bt + (size_t)n0 * KDIM;

  const int srow = lane >> 3;        // 0..7 rows within a 1KB chunk
  const int skel = (lane & 7) * 8;   // k-offset in elements (16B per lane)

  f32x4_t acc[4][4] = {};

  for (int kt = 0; kt < KDIM; kt += BK) {
#pragma unroll
    for (int it = 0; it < 4; ++it) {
      const int c = it * 4 + wave;            // chunk 0..15 (8 rows each)
      const int r = c * 8 + srow;
      stage16(gA + (size_t)r * KDIM + kt + skel, (char*)As + c * 1024);
      stage16(gB + (size_t)r * KDIM + kt + skel, (char*)Bs + c * 1024);
    }
    __syncthreads();
#pragma unroll
    for (int kk = 0; kk < BK; kk += 32) {
      bf16x8_t af[4], bv[4];
#pragma unroll
      for (int i = 0; i < 4; ++i)
        af[i] = *reinterpret_cast<const bf16x8_t*>(
            &As[(wm * 64 + i * 16 + (lane & 15)) * BK + kk + (lane >> 4) * 8]);
#pragma unroll
      for (int j = 0; j < 4; ++j)
        bv[j] = *reinterpret_cast<const bf16x8_t*>(
            &Bs[(wn * 64 + j * 16 + (lane & 15)) * BK + kk + (lane >> 4) * 8]);
#pragma unroll
      for (int i = 0; i < 4; ++i)
#pragma unroll
        for (int j = 0; j < 4; ++j)
          acc[i][j] = __builtin_amdgcn_mfma_f32_16x16x32_bf16(af[i], bv[j],
                                                              acc[i][j], 0, 0, 0);
    }
    __syncthreads();
  }

  // epilogue: D mapping col = lane&15, row = (lane>>4)*4 + r  [m89/m91]
#pragma unroll
  for (int i = 0; i < 4; ++i) {
#pragma unroll
    for (int r = 0; r < 4; ++r) {
      const int row = m0 + wm * 64 + i * 16 + (lane >> 4) * 4 + r;
      if (EPI == 1) {
        const int s0 = subs[2 * row], s1 = subs[2 * row + 1];
#pragma unroll
        for (int j = 0; j < 4; ++j) {
          const int col = n0 + wn * 64 + j * 16 + (lane & 15);
          const int p   = col >> 7;  // PART_SIZE = 128
          const float mult = (float)((s0 == p) + (s1 == p));
          Yb[(size_t)row * PROJ_DIM + col] = f2bf(acc[i][j][r] * mult);
        }
      } else {
#pragma unroll
        for (int j = 0; j < 4; ++j) {
          const int col = n0 + wn * 64 + j * 16 + (lane & 15);
          const size_t o = (size_t)row * EMBED_DIM + col;
          out[o] = base[o] + acc[i][j][r];
        }
      }
    }
  }
}

extern "C" void kernel_launch(void* const* d_in, const int* in_sizes, int n_in,
                              void* d_out, int out_size, void* d_ws, size_t ws_size,
                              hipStream_t stream) {
  const float* base   = (const float*)d_in[0];
  const float* source = (const float*)d_in[1];
  const int*   subs   = (const int*)d_in[2];
  const float* W      = (const float*)d_in[3];
  float* out = (float*)d_out;

  // scratch layout:
  //   delta_bf16 [8192,4096] (64 MB) -> lives in d_out (dead before GEMM2 writes)
  //   ws: Yb [8192,1024] bf16 (16 MB) | Wb [4096,1024] bf16 (8 MB) | WTb [1024,4096] bf16 (8 MB)
  unsigned short* delta = (unsigned short*)d_out;
  char* ws = (char*)d_ws;
  unsigned short* Yb  = (unsigned short*)(ws);
  unsigned short* Wb  = (unsigned short*)(ws + (16u << 20));
  unsigned short* WTb = (unsigned short*)(ws + (24u << 20));

  prep_w<<<dim3(PROJ_DIM / 32, EMBED_DIM / 32), 256, 0, stream>>>(W, Wb, WTb);

  const int n8 = NROWS * EMBED_DIM / 8;
  make_delta<<<2048, 256, 0, stream>>>((const float4*)base, (const float4*)source,
                                       (ushort8_t*)delta, n8);

  // GEMM1: Y = delta @ W   (Bt = W^T rows contiguous in K=4096)
  gemm_bt<1, EMBED_DIM><<<dim3(NROWS / BM, PROJ_DIM / BN), 256, 0, stream>>>(
      delta, WTb, subs, Yb, nullptr, nullptr);

  // GEMM2: out = base + Ymask @ W^T  (Bt = W rows contiguous in K=1024)
  gemm_bt<2, PROJ_DIM><<<dim3(NROWS / BM, EMBED_DIM / BN), 256, 0, stream>>>(
      Yb, Wb, nullptr, nullptr, base, out);
}

// Round 2
// 289.312 us; speedup vs baseline: 1.1021x; 1.1021x over previous
//
#include <hip/hip_runtime.h>
#include <hip/hip_bf16.h>

#define EMBED_DIM 4096
#define PROJ_DIM  1024
#define NROWS     8192
#define NPART     8
#define PARTSZ    128
#define NBUCKET   64
#define MAXTILES  128
#define KSPLIT    4
#define KCHUNK    1024   // EMBED_DIM / KSPLIT
#define KSEL      256    // gathered columns per row

typedef __bf16 bf16x8_t __attribute__((ext_vector_type(8)));
typedef float  f32x4_t  __attribute__((ext_vector_type(4)));
typedef unsigned short ushort8_t __attribute__((ext_vector_type(8)));

__device__ __forceinline__ unsigned short f2bf(float f) {
  unsigned u = __builtin_bit_cast(unsigned, f);
  u += 0x7fffu + ((u >> 16) & 1u);   // round-to-nearest-even
  return (unsigned short)(u >> 16);
}

__device__ __forceinline__ void stage16(const void* g, void* l) {
  __builtin_amdgcn_global_load_lds(
      (const __attribute__((address_space(1))) unsigned int*)g,
      (__attribute__((address_space(3))) unsigned int*)l, 16, 0, 0);
}

// ---- Wb = bf16(W) [4096,1024]; WTb = bf16(W^T) [1024,4096] ----
__global__ __launch_bounds__(256) void prep_w(const float* __restrict__ W,
                                              unsigned short* __restrict__ Wb,
                                              unsigned short* __restrict__ WTb) {
  __shared__ float t[32][33];
  const int px = threadIdx.x & 31;
  const int ty = threadIdx.x >> 5;
  const int p0 = blockIdx.x * 32;
  const int d0 = blockIdx.y * 32;
#pragma unroll
  for (int i = 0; i < 32; i += 8) {
    float v = W[(size_t)(d0 + ty + i) * PROJ_DIM + p0 + px];
    t[ty + i][px] = v;
    Wb[(size_t)(d0 + ty + i) * PROJ_DIM + p0 + px] = f2bf(v);
  }
  __syncthreads();
#pragma unroll
  for (int i = 0; i < 32; i += 8) {
    WTb[(size_t)(p0 + ty + i) * EMBED_DIM + d0 + px] = f2bf(t[px][ty + i]);
  }
}

// ---- delta_bf16 = bf16(source - base) ----
__global__ __launch_bounds__(256) void make_delta(const float4* __restrict__ b,
                                                  const float4* __restrict__ s,
                                                  ushort8_t* __restrict__ d, int n8) {
  for (int i = blockIdx.x * blockDim.x + threadIdx.x; i < n8;
       i += gridDim.x * blockDim.x) {
    float4 b0 = b[2 * i], b1 = b[2 * i + 1];
    float4 s0 = s[2 * i], s1 = s[2 * i + 1];
    ushort8_t o;
    o[0] = f2bf(s0.x - b0.x); o[1] = f2bf(s0.y - b0.y);
    o[2] = f2bf(s0.z - b0.z); o[3] = f2bf(s0.w - b0.w);
    o[4] = f2bf(s1.x - b1.x); o[5] = f2bf(s1.y - b1.y);
    o[6] = f2bf(s1.z - b1.z); o[7] = f2bf(s1.w - b1.w);
    d[i] = o;
  }
}

// ---- bucketing: pair id p = s0*8+s1 per row ----
__global__ void zero_meta(int* __restrict__ hist, int* __restrict__ cursor) {
  int t = threadIdx.x;
  if (t < NBUCKET) hist[t] = 0;
  else if (t < 2 * NBUCKET) cursor[t - NBUCKET] = 0;
}

__global__ void k_hist(const int* __restrict__ subs, int* __restrict__ hist) {
  int r = blockIdx.x * 256 + threadIdx.x;
  if (r < NROWS) atomicAdd(&hist[subs[2 * r] * NPART + subs[2 * r + 1]], 1);
}

// one wave: exclusive scan of hist + tile table build
__global__ void k_scan(const int* __restrict__ hist, int* __restrict__ bucket_off,
                       int* __restrict__ tiles, int* __restrict__ n_tiles) {
  int lane = threadIdx.x;                 // 0..63
  int v = hist[lane];
  int incl = v;
#pragma unroll
  for (int o = 1; o < 64; o <<= 1) { int n = __shfl_up(incl, o); if (lane >= o) incl += n; }
  int excl = incl - v;
  bucket_off[lane] = excl;
  int tc = (v + 127) >> 7;
  int tincl = tc;
#pragma unroll
  for (int o = 1; o < 64; o <<= 1) { int n = __shfl_up(tincl, o); if (lane >= o) tincl += n; }
  int texcl = tincl - tc;
  for (int t = 0; t < tc; ++t) {
    int idx = texcl + t;
    tiles[3 * idx + 0] = excl + t * 128;            // start in permuted order
    tiles[3 * idx + 1] = min(128, v - t * 128);     // row count
    tiles[3 * idx + 2] = lane;                      // bucket id
  }
  if (lane == 63) *n_tiles = tincl;
}

__global__ void k_scatter(const int* __restrict__ subs, const int* __restrict__ bucket_off,
                          int* __restrict__ cursor, int* __restrict__ perm) {
  int r = blockIdx.x * 256 + threadIdx.x;
  if (r < NROWS) {
    int p = subs[2 * r] * NPART + subs[2 * r + 1];
    int pos = bucket_off[p] + atomicAdd(&cursor[p], 1);
    perm[pos] = r;
  }
}

// ---- GEMM1 bucketed, split-K: Ypart[kc][i, 0:256] = delta[perm[i],:] @ Wsel ----
#define BK 64

__global__ __launch_bounds__(256) void gemm1(
    const unsigned short* __restrict__ delta,  // [8192,4096] bf16
    const unsigned short* __restrict__ WTb,    // [1024,4096] bf16
    const int* __restrict__ perm,
    const int* __restrict__ tiles, const int* __restrict__ n_tiles,
    float* __restrict__ Ypart) {               // [KSPLIT][8192][256]
  __shared__ __attribute__((aligned(16))) __bf16 As[128 * BK];
  __shared__ __attribute__((aligned(16))) __bf16 Bs[128 * BK];

  const int tile = blockIdx.x;
  if (tile >= *n_tiles) return;
  const int start = tiles[3 * tile + 0];
  const int cnt   = tiles[3 * tile + 1];
  const int bkt   = tiles[3 * tile + 2];
  const int s     = (blockIdx.y == 0) ? (bkt >> 3) : (bkt & 7);
  const int kbase = blockIdx.z * KCHUNK;

  const int tid  = threadIdx.x;
  const int lane = tid & 63;
  const int wave = tid >> 6;
  const int wm   = wave >> 1;
  const int wn   = wave & 1;
  const int srow = lane >> 3;
  const int skel = (lane & 7) * 8;

  // per-chunk gathered A row pointers (clamped to valid rows)
  const unsigned short* aptr[4];
#pragma unroll
  for (int it = 0; it < 4; ++it) {
    const int c = it * 4 + wave;
    int rl = c * 8 + srow;
    rl = rl < cnt ? rl : 0;
    aptr[it] = delta + (size_t)perm[start + rl] * EMBED_DIM + kbase + skel;
  }
  const unsigned short* gB = WTb + (size_t)(s * PARTSZ) * EMBED_DIM + kbase;

  f32x4_t acc[4][4] = {};

  for (int kt = 0; kt < KCHUNK; kt += BK) {
#pragma unroll
    for (int it = 0; it < 4; ++it) {
      const int c = it * 4 + wave;
      const int r = c * 8 + srow;
      stage16(aptr[it] + kt, (char*)As + c * 1024);
      stage16(gB + (size_t)r * EMBED_DIM + kt + skel, (char*)Bs + c * 1024);
    }
    __syncthreads();
#pragma unroll
    for (int kk = 0; kk < BK; kk += 32) {
      bf16x8_t af[4], bv[4];
#pragma unroll
      for (int i = 0; i < 4; ++i)
        af[i] = *reinterpret_cast<const bf16x8_t*>(
            &As[(wm * 64 + i * 16 + (lane & 15)) * BK + kk + (lane >> 4) * 8]);
#pragma unroll
      for (int j = 0; j < 4; ++j)
        bv[j] = *reinterpret_cast<const bf16x8_t*>(
            &Bs[(wn * 64 + j * 16 + (lane & 15)) * BK + kk + (lane >> 4) * 8]);
#pragma unroll
      for (int i = 0; i < 4; ++i)
#pragma unroll
        for (int j = 0; j < 4; ++j)
          acc[i][j] = __builtin_amdgcn_mfma_f32_16x16x32_bf16(af[i], bv[j],
                                                              acc[i][j], 0, 0, 0);
    }
    __syncthreads();
  }

  float* Yo = Ypart + (size_t)blockIdx.z * NROWS * KSEL;
#pragma unroll
  for (int i = 0; i < 4; ++i) {
#pragma unroll
    for (int r = 0; r < 4; ++r) {
      const int row_local = wm * 64 + i * 16 + (lane >> 4) * 4 + r;
      if (row_local < cnt) {
#pragma unroll
        for (int j = 0; j < 4; ++j) {
          const int col = blockIdx.y * 128 + wn * 64 + j * 16 + (lane & 15);
          Yo[(size_t)(start + row_local) * KSEL + col] = acc[i][j][r];
        }
      }
    }
  }
}

// ---- combine split-K partials -> Ysel bf16 [8192+128, 256] ----
__global__ __launch_bounds__(256) void combine(const float* __restrict__ Yp,
                                               unsigned short* __restrict__ Ysel) {
  const int total = NROWS * KSEL / 4;
  for (int i = blockIdx.x * blockDim.x + threadIdx.x; i < total;
       i += gridDim.x * blockDim.x) {
    float4 a = ((const float4*)Yp)[i];
    float4 b = ((const float4*)(Yp + (size_t)NROWS * KSEL))[i];
    float4 c = ((const float4*)(Yp + (size_t)2 * NROWS * KSEL))[i];
    float4 d = ((const float4*)(Yp + (size_t)3 * NROWS * KSEL))[i];
    ushort4 o;
    o.x = f2bf(a.x + b.x + c.x + d.x);
    o.y = f2bf(a.y + b.y + c.y + d.y);
    o.z = f2bf(a.z + b.z + c.z + d.z);
    o.w = f2bf(a.w + b.w + c.w + d.w);
    ((ushort4*)Ysel)[i] = o;
  }
}

// ---- GEMM2 bucketed: out[perm[i],:] = base[perm[i],:] + Ysel[i,:] @ Wsel^T ----
__global__ __launch_bounds__(256) void gemm2(
    const unsigned short* __restrict__ Ysel,   // [8192+128, 256] bf16
    const unsigned short* __restrict__ Wb,     // [4096,1024] bf16
    const int* __restrict__ perm,
    const int* __restrict__ tiles, const int* __restrict__ n_tiles,
    const float* __restrict__ base, float* __restrict__ out) {
  __shared__ __attribute__((aligned(16))) __bf16 As[128 * BK];
  __shared__ __attribute__((aligned(16))) __bf16 Bs[128 * BK];

  const int tile = blockIdx.x;
  if (tile >= *n_tiles) return;
  const int start = tiles[3 * tile + 0];
  const int cnt   = tiles[3 * tile + 1];
  const int bkt   = tiles[3 * tile + 2];
  const int s0    = bkt >> 3, s1 = bkt & 7;
  const int n0    = blockIdx.y * 128;

  const int tid  = threadIdx.x;
  const int lane = tid & 63;
  const int wave = tid >> 6;
  const int wm   = wave >> 1;
  const int wn   = wave & 1;
  const int srow = lane >> 3;
  const int skel = (lane & 7) * 8;

  const unsigned short* gA = Ysel + (size_t)start * KSEL;

  f32x4_t acc[4][4] = {};

#pragma unroll
  for (int kt = 0; kt < KSEL; kt += BK) {
    const int sp   = (kt < 128) ? s0 : s1;
    const int coff = sp * PARTSZ + (kt & 64);
#pragma unroll
    for (int it = 0; it < 4; ++it) {
      const int c = it * 4 + wave;
      const int r = c * 8 + srow;
      stage16(gA + (size_t)r * KSEL + kt + skel, (char*)As + c * 1024);
      stage16(Wb + (size_t)(n0 + r) * PROJ_DIM + coff + skel, (char*)Bs + c * 1024);
    }
    __syncthreads();
#pragma unroll
    for (int kk = 0; kk < BK; kk += 32) {
      bf16x8_t af[4], bv[4];
#pragma unroll
      for (int i = 0; i < 4; ++i)
        af[i] = *reinterpret_cast<const bf16x8_t*>(
            &As[(wm * 64 + i * 16 + (lane & 15)) * BK + kk + (lane >> 4) * 8]);
#pragma unroll
      for (int j = 0; j < 4; ++j)
        bv[j] = *reinterpret_cast<const bf16x8_t*>(
            &Bs[(wn * 64 + j * 16 + (lane & 15)) * BK + kk + (lane >> 4) * 8]);
#pragma unroll
      for (int i = 0; i < 4; ++i)
#pragma unroll
        for (int j = 0; j < 4; ++j)
          acc[i][j] = __builtin_amdgcn_mfma_f32_16x16x32_bf16(af[i], bv[j],
                                                              acc[i][j], 0, 0, 0);
    }
    __syncthreads();
  }

#pragma unroll
  for (int i = 0; i < 4; ++i) {
#pragma unroll
    for (int r = 0; r < 4; ++r) {
      const int row_local = wm * 64 + i * 16 + (lane >> 4) * 4 + r;
      if (row_local < cnt) {
        const int grow = perm[start + row_local];
#pragma unroll
        for (int j = 0; j < 4; ++j) {
          const int col = n0 + wn * 64 + j * 16 + (lane & 15);
          const size_t o = (size_t)grow * EMBED_DIM + col;
          out[o] = base[o] + acc[i][j][r];
        }
      }
    }
  }
}

extern "C" void kernel_launch(void* const* d_in, const int* in_sizes, int n_in,
                              void* d_out, int out_size, void* d_ws, size_t ws_size,
                              hipStream_t stream) {
  const float* base   = (const float*)d_in[0];
  const float* source = (const float*)d_in[1];
  const int*   subs   = (const int*)d_in[2];
  const float* W      = (const float*)d_in[3];
  float* out = (float*)d_out;

  // d_out scratch (dead before gemm2 writes out):
  //   delta bf16 [8192,4096] @ 0        (64 MB)
  //   Ypart f32 [4][8192,256] @ 64 MB   (32 MB)
  unsigned short* delta = (unsigned short*)d_out;
  float* Ypart = (float*)((char*)d_out + (64u << 20));

  // ws: Wb 8MB | WTb 8MB | Ysel 4.3MB | meta
  char* ws = (char*)d_ws;
  unsigned short* Wb   = (unsigned short*)(ws);
  unsigned short* WTb  = (unsigned short*)(ws + (8u << 20));
  unsigned short* Ysel = (unsigned short*)(ws + (16u << 20));
  char* meta = ws + (21u << 20);
  int* hist       = (int*)(meta);
  int* cursor     = (int*)(meta + 256);
  int* bucket_off = (int*)(meta + 512);
  int* n_tiles    = (int*)(meta + 768);
  int* tiles      = (int*)(meta + 1024);          // 128*3 ints
  int* perm       = (int*)(meta + 4096);          // 8192 ints

  prep_w<<<dim3(PROJ_DIM / 32, EMBED_DIM / 32), 256, 0, stream>>>(W, Wb, WTb);

  const int n8 = NROWS * EMBED_DIM / 8;
  make_delta<<<2048, 256, 0, stream>>>((const float4*)base, (const float4*)source,
                                       (ushort8_t*)delta, n8);

  zero_meta<<<1, 128, 0, stream>>>(hist, cursor);
  k_hist<<<NROWS / 256, 256, 0, stream>>>(subs, hist);
  k_scan<<<1, 64, 0, stream>>>(hist, bucket_off, tiles, n_tiles);
  k_scatter<<<NROWS / 256, 256, 0, stream>>>(subs, bucket_off, cursor, perm);

  gemm1<<<dim3(MAXTILES, 2, KSPLIT), 256, 0, stream>>>(delta, WTb, perm, tiles,
                                                       n_tiles, Ypart);
  combine<<<1024, 256, 0, stream>>>(Ypart, Ysel);

  gemm2<<<dim3(MAXTILES, EMBED_DIM / 128), 256, 0, stream>>>(Ysel, Wb, perm, tiles,
                                                             n_tiles, base, out);
}

// Round 3
// 256.331 us; speedup vs baseline: 1.2439x; 1.1287x over previous
//
#include <hip/hip_runtime.h>
#include <hip/hip_bf16.h>

#define EMBED_DIM 4096
#define PROJ_DIM  1024
#define NROWS     8192
#define NPART     8
#define PARTSZ    128
#define MAXTILES  128
#define KSPLIT    4
#define KCHUNK    1024   // EMBED_DIM / KSPLIT
#define KSEL      256    // gathered columns per row
#define BK        64

typedef __bf16 bf16x8_t __attribute__((ext_vector_type(8)));
typedef float  f32x4_t  __attribute__((ext_vector_type(4)));
typedef unsigned short ushort8_t __attribute__((ext_vector_type(8)));

__device__ __forceinline__ unsigned short f2bf(float f) {
  unsigned u = __builtin_bit_cast(unsigned, f);
  u += 0x7fffu + ((u >> 16) & 1u);   // round-to-nearest-even
  return (unsigned short)(u >> 16);
}

__device__ __forceinline__ void stage16(const void* g, void* l) {
  __builtin_amdgcn_global_load_lds(
      (const __attribute__((address_space(1))) unsigned int*)g,
      (__attribute__((address_space(3))) unsigned int*)l, 16, 0, 0);
}

// ---- Wb = bf16(W) [4096,1024]; WTb = bf16(W^T) [1024,4096] ----
__global__ __launch_bounds__(256) void prep_w(const float* __restrict__ W,
                                              unsigned short* __restrict__ Wb,
                                              unsigned short* __restrict__ WTb) {
  __shared__ float t[32][33];
  const int px = threadIdx.x & 31;
  const int ty = threadIdx.x >> 5;
  const int p0 = blockIdx.x * 32;
  const int d0 = blockIdx.y * 32;
#pragma unroll
  for (int i = 0; i < 32; i += 8) {
    float v = W[(size_t)(d0 + ty + i) * PROJ_DIM + p0 + px];
    t[ty + i][px] = v;
    Wb[(size_t)(d0 + ty + i) * PROJ_DIM + p0 + px] = f2bf(v);
  }
  __syncthreads();
#pragma unroll
  for (int i = 0; i < 32; i += 8) {
    WTb[(size_t)(p0 + ty + i) * EMBED_DIM + d0 + px] = f2bf(t[px][ty + i]);
  }
}

// ---- delta_bf16 = bf16(source - base) ----
__global__ __launch_bounds__(256) void make_delta(const float4* __restrict__ b,
                                                  const float4* __restrict__ s,
                                                  ushort8_t* __restrict__ d, int n8) {
  for (int i = blockIdx.x * blockDim.x + threadIdx.x; i < n8;
       i += gridDim.x * blockDim.x) {
    float4 b0 = b[2 * i], b1 = b[2 * i + 1];
    float4 s0 = s[2 * i], s1 = s[2 * i + 1];
    ushort8_t o;
    o[0] = f2bf(s0.x - b0.x); o[1] = f2bf(s0.y - b0.y);
    o[2] = f2bf(s0.z - b0.z); o[3] = f2bf(s0.w - b0.w);
    o[4] = f2bf(s1.x - b1.x); o[5] = f2bf(s1.y - b1.y);
    o[6] = f2bf(s1.z - b1.z); o[7] = f2bf(s1.w - b1.w);
    d[i] = o;
  }
}

// ---- single-block bucketing: hist -> scan -> tile table -> scatter ----
__global__ __launch_bounds__(1024) void k_bucket(const int* __restrict__ subs,
                                                 int* __restrict__ tiles,
                                                 int* __restrict__ n_tiles,
                                                 int* __restrict__ perm) {
  __shared__ int h[64], off[64], cur[64];
  const int t = threadIdx.x;
  if (t < 64) h[t] = 0;
  __syncthreads();
  for (int r = t; r < NROWS; r += 1024)
    atomicAdd(&h[subs[2 * r] * NPART + subs[2 * r + 1]], 1);
  __syncthreads();
  if (t < 64) {  // threads 0..63 == wave 0
    int v = h[t], incl = v;
#pragma unroll
    for (int o = 1; o < 64; o <<= 1) { int n = __shfl_up(incl, o); if (t >= o) incl += n; }
    int excl = incl - v;
    off[t] = excl; cur[t] = 0;
    int tc = (v + 127) >> 7, tincl = tc;
#pragma unroll
    for (int o = 1; o < 64; o <<= 1) { int n = __shfl_up(tincl, o); if (t >= o) tincl += n; }
    int texcl = tincl - tc;
    for (int k = 0; k < tc; ++k) {
      tiles[3 * (texcl + k) + 0] = excl + k * 128;
      tiles[3 * (texcl + k) + 1] = min(128, v - k * 128);
      tiles[3 * (texcl + k) + 2] = t;
    }
    if (t == 63) *n_tiles = tincl;
  }
  __syncthreads();
  for (int r = t; r < NROWS; r += 1024) {
    int p = subs[2 * r] * NPART + subs[2 * r + 1];
    perm[off[p] + atomicAdd(&cur[p], 1)] = r;
  }
}

// ---- GEMM1 bucketed, split-K, 2-phase dbuf:
//      Ypart[kz][i, 0:256] = delta[perm[i], kz*1024:(kz+1)*1024] @ Wsel ----
__global__ __launch_bounds__(256) void gemm1(
    const unsigned short* __restrict__ delta,  // [8192,4096] bf16
    const unsigned short* __restrict__ WTb,    // [1024,4096] bf16
    const int* __restrict__ perm,
    const int* __restrict__ tiles, const int* __restrict__ n_tiles,
    float* __restrict__ Ypart) {               // [KSPLIT][8192][256]
  __shared__ __attribute__((aligned(16))) __bf16 As[2][128 * BK];
  __shared__ __attribute__((aligned(16))) __bf16 Bs[2][128 * BK];

  const int tile = blockIdx.x;
  if (tile >= *n_tiles) return;
  const int start = tiles[3 * tile + 0];
  const int cnt   = tiles[3 * tile + 1];
  const int bkt   = tiles[3 * tile + 2];
  const int s     = (blockIdx.y == 0) ? (bkt >> 3) : (bkt & 7);
  const int kbase = blockIdx.z * KCHUNK;

  const int lane = threadIdx.x & 63;
  const int wave = threadIdx.x >> 6;
  const int wm   = wave >> 1;
  const int wn   = wave & 1;
  const int srow = lane >> 3;
  const int skel = (lane & 7) * 8;

  // gathered A row pointers + B row pointers (wave-cooperative chunks)
  const unsigned short* aptr[4];
  const unsigned short* bptr[4];
#pragma unroll
  for (int it = 0; it < 4; ++it) {
    const int c = it * 4 + wave;
    int rl = c * 8 + srow;
    rl = rl < cnt ? rl : 0;
    aptr[it] = delta + (size_t)perm[start + rl] * EMBED_DIM + kbase + skel;
    bptr[it] = WTb + (size_t)(s * PARTSZ + c * 8 + srow) * EMBED_DIM + kbase + skel;
  }

#define STAGE1(buf, kt)                                                \
  {                                                                    \
    _Pragma("unroll") for (int it = 0; it < 4; ++it) {                 \
      const int c = it * 4 + wave;                                     \
      stage16(aptr[it] + (kt), (char*)&As[buf][0] + c * 1024);         \
      stage16(bptr[it] + (kt), (char*)&Bs[buf][0] + c * 1024);         \
    }                                                                  \
  }

  f32x4_t acc[4][4] = {};

  STAGE1(0, 0);
  __syncthreads();
  int cur = 0;
  for (int kt = 0; kt < KCHUNK; kt += BK) {
    if (kt + BK < KCHUNK) STAGE1(cur ^ 1, kt + BK);
#pragma unroll
    for (int kk = 0; kk < BK; kk += 32) {
      bf16x8_t af[4], bv[4];
#pragma unroll
      for (int i = 0; i < 4; ++i)
        af[i] = *reinterpret_cast<const bf16x8_t*>(
            &As[cur][(wm * 64 + i * 16 + (lane & 15)) * BK + kk + (lane >> 4) * 8]);
#pragma unroll
      for (int j = 0; j < 4; ++j)
        bv[j] = *reinterpret_cast<const bf16x8_t*>(
            &Bs[cur][(wn * 64 + j * 16 + (lane & 15)) * BK + kk + (lane >> 4) * 8]);
      // swapped operands -> transposed D: lane holds 4 consecutive N-cols of one M-row
#pragma unroll
      for (int i = 0; i < 4; ++i)
#pragma unroll
        for (int j = 0; j < 4; ++j)
          acc[i][j] = __builtin_amdgcn_mfma_f32_16x16x32_bf16(bv[j], af[i],
                                                              acc[i][j], 0, 0, 0);
    }
    __syncthreads();
    cur ^= 1;
  }

  float* Yo = Ypart + (size_t)blockIdx.z * NROWS * KSEL;
#pragma unroll
  for (int i = 0; i < 4; ++i) {
    const int row_local = wm * 64 + i * 16 + (lane & 15);
    if (row_local < cnt) {
#pragma unroll
      for (int j = 0; j < 4; ++j) {
        const int col = blockIdx.y * 128 + wn * 64 + j * 16 + (lane >> 4) * 4;
        *reinterpret_cast<f32x4_t*>(&Yo[(size_t)(start + row_local) * KSEL + col]) =
            acc[i][j];
      }
    }
  }
}

// ---- combine split-K partials -> Ysel bf16 [8192, 256] ----
__global__ __launch_bounds__(256) void combine(const float* __restrict__ Yp,
                                               unsigned short* __restrict__ Ysel) {
  const int total = NROWS * KSEL / 4;
  for (int i = blockIdx.x * blockDim.x + threadIdx.x; i < total;
       i += gridDim.x * blockDim.x) {
    float4 a = ((const float4*)Yp)[i];
    float4 b = ((const float4*)(Yp + (size_t)NROWS * KSEL))[i];
    float4 c = ((const float4*)(Yp + (size_t)2 * NROWS * KSEL))[i];
    float4 d = ((const float4*)(Yp + (size_t)3 * NROWS * KSEL))[i];
    ushort4 o;
    o.x = f2bf(a.x + b.x + c.x + d.x);
    o.y = f2bf(a.y + b.y + c.y + d.y);
    o.z = f2bf(a.z + b.z + c.z + d.z);
    o.w = f2bf(a.w + b.w + c.w + d.w);
    ((ushort4*)Ysel)[i] = o;
  }
}

// ---- GEMM2 bucketed, 2-phase dbuf:
//      out[perm[i],:] = base[perm[i],:] + Ysel[i,:] @ Wsel^T ----
__global__ __launch_bounds__(256) void gemm2(
    const unsigned short* __restrict__ Ysel,   // [8192, 256] bf16
    const unsigned short* __restrict__ Wb,     // [4096,1024] bf16
    const int* __restrict__ perm,
    const int* __restrict__ tiles, const int* __restrict__ n_tiles,
    const float* __restrict__ base, float* __restrict__ out) {
  __shared__ __attribute__((aligned(16))) __bf16 As[2][128 * BK];
  __shared__ __attribute__((aligned(16))) __bf16 Bs[2][128 * BK];

  const int tile = blockIdx.x;
  if (tile >= *n_tiles) return;
  const int start = tiles[3 * tile + 0];
  const int cnt   = tiles[3 * tile + 1];
  const int bkt   = tiles[3 * tile + 2];
  const int s0    = bkt >> 3, s1 = bkt & 7;
  const int n0    = blockIdx.y * 128;

  const int lane = threadIdx.x & 63;
  const int wave = threadIdx.x >> 6;
  const int wm   = wave >> 1;
  const int wn   = wave & 1;
  const int srow = lane >> 3;
  const int skel = (lane & 7) * 8;

  const unsigned short* gA = Ysel + (size_t)start * KSEL;

#define STAGE2(buf, kt)                                                        \
  {                                                                            \
    const int sp   = ((kt) < 128) ? s0 : s1;                                   \
    const int coff = sp * PARTSZ + ((kt) & 64);                                \
    _Pragma("unroll") for (int it = 0; it < 4; ++it) {                         \
      const int c = it * 4 + wave;                                             \
      const int r = c * 8 + srow;                                              \
      stage16(gA + (size_t)r * KSEL + (kt) + skel,                             \
              (char*)&As[buf][0] + c * 1024);                                  \
      stage16(Wb + (size_t)(n0 + r) * PROJ_DIM + coff + skel,                  \
              (char*)&Bs[buf][0] + c * 1024);                                  \
    }                                                                          \
  }

  f32x4_t acc[4][4] = {};

  STAGE2(0, 0);
  __syncthreads();
  int cur = 0;
#pragma unroll
  for (int kt = 0; kt < KSEL; kt += BK) {
    if (kt + BK < KSEL) STAGE2(cur ^ 1, kt + BK);
#pragma unroll
    for (int kk = 0; kk < BK; kk += 32) {
      bf16x8_t af[4], bv[4];
#pragma unroll
      for (int i = 0; i < 4; ++i)
        af[i] = *reinterpret_cast<const bf16x8_t*>(
            &As[cur][(wm * 64 + i * 16 + (lane & 15)) * BK + kk + (lane >> 4) * 8]);
#pragma unroll
      for (int j = 0; j < 4; ++j)
        bv[j] = *reinterpret_cast<const bf16x8_t*>(
            &Bs[cur][(wn * 64 + j * 16 + (lane & 15)) * BK + kk + (lane >> 4) * 8]);
#pragma unroll
      for (int i = 0; i < 4; ++i)
#pragma unroll
        for (int j = 0; j < 4; ++j)
          acc[i][j] = __builtin_amdgcn_mfma_f32_16x16x32_bf16(bv[j], af[i],
                                                              acc[i][j], 0, 0, 0);
    }
    __syncthreads();
    cur ^= 1;
  }

#pragma unroll
  for (int i = 0; i < 4; ++i) {
    const int row_local = wm * 64 + i * 16 + (lane & 15);
    if (row_local < cnt) {
      const int grow = perm[start + row_local];
#pragma unroll
      for (int j = 0; j < 4; ++j) {
        const int col = n0 + wn * 64 + j * 16 + (lane >> 4) * 4;
        const size_t o = (size_t)grow * EMBED_DIM + col;
        f32x4_t b4 = *reinterpret_cast<const f32x4_t*>(&base[o]);
        f32x4_t r4 = acc[i][j] + b4;
        *reinterpret_cast<f32x4_t*>(&out[o]) = r4;
      }
    }
  }
}

extern "C" void kernel_launch(void* const* d_in, const int* in_sizes, int n_in,
                              void* d_out, int out_size, void* d_ws, size_t ws_size,
                              hipStream_t stream) {
  const float* base   = (const float*)d_in[0];
  const float* source = (const float*)d_in[1];
  const int*   subs   = (const int*)d_in[2];
  const float* W      = (const float*)d_in[3];
  float* out = (float*)d_out;

  // d_out scratch (dead before gemm2 writes out):
  //   delta bf16 [8192,4096] @ 0        (64 MB)
  //   Ypart f32 [4][8192,256] @ 64 MB   (32 MB)
  unsigned short* delta = (unsigned short*)d_out;
  float* Ypart = (float*)((char*)d_out + (64u << 20));

  // ws: Wb 8MB | WTb 8MB | Ysel 4MB | meta
  char* ws = (char*)d_ws;
  unsigned short* Wb   = (unsigned short*)(ws);
  unsigned short* WTb  = (unsigned short*)(ws + (8u << 20));
  unsigned short* Ysel = (unsigned short*)(ws + (16u << 20));
  char* meta = ws + (21u << 20);
  int* n_tiles = (int*)(meta);
  int* tiles   = (int*)(meta + 256);   // 128*3 ints
  int* perm    = (int*)(meta + 4096);  // 8192 ints

  k_bucket<<<1, 1024, 0, stream>>>(subs, tiles, n_tiles, perm);

  prep_w<<<dim3(PROJ_DIM / 32, EMBED_DIM / 32), 256, 0, stream>>>(W, Wb, WTb);

  const int n8 = NROWS * EMBED_DIM / 8;
  make_delta<<<2048, 256, 0, stream>>>((const float4*)base, (const float4*)source,
                                       (ushort8_t*)delta, n8);

  gemm1<<<dim3(MAXTILES, 2, KSPLIT), 256, 0, stream>>>(delta, WTb, perm, tiles,
                                                       n_tiles, Ypart);
  combine<<<1024, 256, 0, stream>>>(Ypart, Ysel);

  gemm2<<<dim3(MAXTILES, EMBED_DIM / 128), 256, 0, stream>>>(Ysel, Wb, perm, tiles,
                                                             n_tiles, base, out);
}